// Round 5
// baseline (87.047 us; speedup 1.0000x reference)
//
#include <hip/hip_runtime.h>

#define NGT 30000
#define GT_TILE 1024
#define NBLK_G 30            // ceil(30000/1024)
#define CHUNK 64
#define NCHUNK 52            // m0: 3 chunks, m1: 10, m2: 39
#define RB 128               // reduce blocks

// ---------------------------------------------------------------------------
// Fused single-pass chamfer: grid = (NBLK_G, NCHUNK), block = 256.
// Each thread: 4 gt points in registers; pred chunk of 64 in LDS (float4+norm).
// Each pair distance is computed ONCE and feeds BOTH sides:
//   - gmin[k]: running min over preds for this thread's gt points
//   - pm[j]  : min over this thread's 4 gt points for pred j (static index,
//              full unroll -> registers)
// Then pm[] is reduced across the 64 lanes with a register-halving butterfly
// (select + shfl_xor + min, log2(64) levels); lane l ends with pred l's min
// over the wave's 256 gt points -> global atomicMin.
// atomicMin on int bits of non-negative floats: exact, order-independent.
// Padded preds carry w=3e38 sentinel so they never win a min.
// ---------------------------------------------------------------------------
__global__ __launch_bounds__(256) void chamfer_kernel(
    const float* __restrict__ gt,
    const float* __restrict__ pbd0,
    const float* __restrict__ pbd1,
    const float* __restrict__ pbd2,
    float* __restrict__ gtmin,     // [3*NGT] pre-init 0x7f
    float* __restrict__ predmin)   // [3240]  pre-init 0x7f
{
    __shared__ float4 spred[CHUNK];

    const int tid = threadIdx.x;
    const int c = blockIdx.y;

    int mesh, cidx;
    if (c < 3)       { mesh = 0; cidx = c; }
    else if (c < 13) { mesh = 1; cidx = c - 3; }
    else             { mesh = 2; cidx = c - 13; }
    const int coff = cidx * CHUNK;
    const int n    = (mesh == 0) ? 156 : (mesh == 1) ? 618 : 2466;
    const int poff = (mesh == 0) ? 0   : (mesh == 1) ? 156 : 774;
    const float* pred = (mesh == 0) ? pbd0 : (mesh == 1) ? pbd1 : pbd2;
    const int np = min(CHUNK, n - coff);

    if (tid < CHUNK) {
        float4 v = make_float4(0.f, 0.f, 0.f, 3.0e38f);   // sentinel pred
        if (tid < np) {
            const int j = coff + tid;
            float px = pred[3*j], py = pred[3*j+1], pz = pred[3*j+2];
            v = make_float4(px, py, pz, px*px + py*py + pz*pz);
        }
        spred[tid] = v;
    }

    const int gbase = blockIdx.x * GT_TILE;
    float gx[4], gy[4], gz[4], g2[4], gmin[4];
    #pragma unroll
    for (int k = 0; k < 4; ++k) {
        const int g = gbase + k * 256 + tid;
        float x = 1e18f, y = 1e18f, z = 1e18f;   // sentinel gt: huge, finite
        if (g < NGT) { x = gt[3*g]; y = gt[3*g+1]; z = gt[3*g+2]; }
        gx[k] = x; gy[k] = y; gz[k] = z;
        g2[k] = x*x + y*y + z*z;
        gmin[k] = 3.0e38f;
    }
    __syncthreads();

    // ---- fused main loop: one distance per pair, serves both sides ----
    float pm[CHUNK];
    #pragma unroll
    for (int j = 0; j < CHUNK; ++j) {
        const float4 p = spred[j];                 // broadcast ds_read_b128
        float d[4];
        #pragma unroll
        for (int k = 0; k < 4; ++k) {
            float dot = gx[k]*p.x + gy[k]*p.y + gz[k]*p.z;
            float t = __fmaf_rn(dot, -2.0f, p.w);  // p2 - 2*dot
            d[k] = t + g2[k];                      // full squared distance
            gmin[k] = fminf(gmin[k], d[k]);
        }
        pm[j] = fminf(fminf(d[0], d[1]), fminf(d[2], d[3]));
    }

    // gt-side atomics (full distances already include g2)
    #pragma unroll
    for (int k = 0; k < 4; ++k) {
        const int g = gbase + k * 256 + tid;
        if (g < NGT)
            atomicMin((int*)(gtmin + mesh * NGT + g), __float_as_int(gmin[k]));
    }

    // ---- pred-side: register-halving butterfly across 64 lanes ----
    const int lane = tid & 63;
    float r32[32];
    #pragma unroll
    for (int j = 0; j < 32; ++j) {
        float a = (lane & 32) ? pm[j + 32] : pm[j];
        r32[j] = fminf(a, __shfl_xor(a, 32, 64));
    }
    float r16[16];
    #pragma unroll
    for (int j = 0; j < 16; ++j) {
        float a = (lane & 16) ? r32[j + 16] : r32[j];
        r16[j] = fminf(a, __shfl_xor(a, 16, 64));
    }
    float r8[8];
    #pragma unroll
    for (int j = 0; j < 8; ++j) {
        float a = (lane & 8) ? r16[j + 8] : r16[j];
        r8[j] = fminf(a, __shfl_xor(a, 8, 64));
    }
    float r4[4];
    #pragma unroll
    for (int j = 0; j < 4; ++j) {
        float a = (lane & 4) ? r8[j + 4] : r8[j];
        r4[j] = fminf(a, __shfl_xor(a, 4, 64));
    }
    float r2[2];
    #pragma unroll
    for (int j = 0; j < 2; ++j) {
        float a = (lane & 2) ? r4[j + 2] : r4[j];
        r2[j] = fminf(a, __shfl_xor(a, 2, 64));
    }
    {
        float a = (lane & 1) ? r2[1] : r2[0];
        float r = fminf(a, __shfl_xor(a, 1, 64));
        // lane l holds min over this wave's 256 gt points for pred l
        if (lane < np)
            atomicMin((int*)(predmin + poff + coff + lane), __float_as_int(r));
    }
}

// ---------------------------------------------------------------------------
// Partial reduce: gtmin/predmin sums + edge + laplace, RB blocks x 256.
// Deterministic: fixed index slices, fixed-order block tree reduce.
// ---------------------------------------------------------------------------
__global__ __launch_bounds__(256) void partial_kernel(
    const float* __restrict__ pc0, const float* __restrict__ pc1, const float* __restrict__ pc2,
    const float* __restrict__ pbd0, const float* __restrict__ pbd1, const float* __restrict__ pbd2,
    const int* __restrict__ ed0, const int* __restrict__ ed1, const int* __restrict__ ed2,
    const int* __restrict__ li0, const int* __restrict__ li1, const int* __restrict__ li2,
    const float* __restrict__ gtmin, const float* __restrict__ predmin,
    float* __restrict__ partials)   // [RB*4]
{
    const int   NVs[3]   = {156, 618, 2466};
    const int   NEs[3]   = {462, 1848, 7392};
    const int   poffs[3] = {0, 156, 774};
    const int   eoffs[3] = {0, 462, 2310};
    const float lapc[3]  = {0.2f, 1.0f, 1.0f};
    const float* pcs[3]  = {pc0, pc1, pc2};
    const float* pbds[3] = {pbd0, pbd1, pbd2};
    const int*   eds[3]  = {ed0, ed1, ed2};
    const int*   lis[3]  = {li0, li1, li2};

    const int tid = threadIdx.x;
    const int stride = gridDim.x * 256;
    float ch = 0.f, ed = 0.f, lp = 0.f;

    // index space: [0,90000) gtmin | [90000,93240) predmin |
    //              [93240,102942) edges | [102942,106182) laplace verts
    for (int idx = blockIdx.x * 256 + tid; idx < 106182; idx += stride) {
        if (idx < 90000) {
            ch += gtmin[idx] * (1.0f / 30000.0f);
        } else if (idx < 93240) {
            int p = idx - 90000;
            int m = (p < 156) ? 0 : (p < 774) ? 1 : 2;
            ch += predmin[p] * (1.0f / (float)NVs[m]);
        } else if (idx < 102942) {
            int e = idx - 93240;
            int m = (e < 462) ? 0 : (e < 2310) ? 1 : 2;
            int el = e - eoffs[m];
            const int* E = eds[m];
            const float* P = pcs[m];
            int a = E[2*el], b = E[2*el+1];
            float dx = P[3*a]   - P[3*b];
            float dy = P[3*a+1] - P[3*b+1];
            float dz = P[3*a+2] - P[3*b+2];
            ed += (dx*dx + dy*dy + dz*dz) * (300.0f / (float)NEs[m]);
        } else {
            int v = idx - 102942;
            int m = (v < 156) ? 0 : (v < 774) ? 1 : 2;
            int vl = v - poffs[m];
            const int* L = lis[m];
            const float* PB = pbds[m];
            const float* PC = pcs[m];
            float mvx = PB[3*vl]   - PC[3*vl];
            float mvy = PB[3*vl+1] - PC[3*vl+1];
            float mvz = PB[3*vl+2] - PC[3*vl+2];
            float sx = 0.f, sy = 0.f, sz = 0.f;
            #pragma unroll
            for (int k = 0; k < 8; ++k) {
                int nb = L[10*vl + k];
                if (nb >= 0) {
                    sx += PB[3*nb]   - PC[3*nb];
                    sy += PB[3*nb+1] - PC[3*nb+1];
                    sz += PB[3*nb+2] - PC[3*nb+2];
                }
            }
            float invdeg = 1.0f / (float)L[10*vl + 9];
            float dx = mvx - sx * invdeg;
            float dy = mvy - sy * invdeg;
            float dz = mvz - sz * invdeg;
            float t = dx*dx + dy*dy + dz*dz;
            if (m > 0) t += mvx*mvx + mvy*mvy + mvz*mvz;
            lp += t * (lapc[m] / (float)NVs[m]);
        }
    }

    __shared__ float sred[12];
    for (int off = 32; off; off >>= 1) {
        ch += __shfl_down(ch, off, 64);
        ed += __shfl_down(ed, off, 64);
        lp += __shfl_down(lp, off, 64);
    }
    const int lane = tid & 63, wid = tid >> 6;
    if (lane == 0) { sred[wid] = ch; sred[4 + wid] = ed; sred[8 + wid] = lp; }
    __syncthreads();
    if (tid == 0) {
        partials[blockIdx.x * 4 + 0] = sred[0] + sred[1] + sred[2] + sred[3];
        partials[blockIdx.x * 4 + 1] = sred[4] + sred[5] + sred[6] + sred[7];
        partials[blockIdx.x * 4 + 2] = sred[8] + sred[9] + sred[10] + sred[11];
    }
}

// ---------------------------------------------------------------------------
// Final: sum RB partials, write 4 outputs. 1 block x 128.
// ---------------------------------------------------------------------------
__global__ __launch_bounds__(128) void final_kernel(
    const float* __restrict__ partials, float* __restrict__ out)
{
    const int tid = threadIdx.x;
    float ch = partials[4*tid], ed = partials[4*tid+1], lp = partials[4*tid+2];
    __shared__ float s[6];
    for (int off = 32; off; off >>= 1) {
        ch += __shfl_down(ch, off, 64);
        ed += __shfl_down(ed, off, 64);
        lp += __shfl_down(lp, off, 64);
    }
    if ((tid & 63) == 0) {
        int w = tid >> 6;
        s[w] = ch; s[2 + w] = ed; s[4 + w] = lp;
    }
    __syncthreads();
    if (tid == 0) {
        float c = s[0] + s[1], e = s[2] + s[3], l = s[4] + s[5];
        out[0] = 100.0f * c + 0.1f * e + 0.3f * l;
        out[1] = c;
        out[2] = e;
        out[3] = l;
    }
}

extern "C" void kernel_launch(void* const* d_in, const int* in_sizes, int n_in,
                              void* d_out, int out_size, void* d_ws, size_t ws_size,
                              hipStream_t stream) {
    const float* gt   = (const float*)d_in[0];
    const float* pc0  = (const float*)d_in[1];
    const float* pbd0 = (const float*)d_in[2];
    const int*   ed0  = (const int*)  d_in[3];
    const int*   li0  = (const int*)  d_in[4];
    const float* pc1  = (const float*)d_in[5];
    const float* pbd1 = (const float*)d_in[6];
    const int*   ed1  = (const int*)  d_in[7];
    const int*   li1  = (const int*)  d_in[8];
    const float* pc2  = (const float*)d_in[9];
    const float* pbd2 = (const float*)d_in[10];
    const int*   ed2  = (const int*)  d_in[11];
    const int*   li2  = (const int*)  d_in[12];

    float* ws       = (float*)d_ws;
    float* gtmin    = ws;                    // 3*NGT floats
    float* predmin  = ws + 3 * NGT;          // 3240 floats
    float* partials = ws + 3 * NGT + 3240;   // RB*4 floats
    float* out      = (float*)d_out;

    hipMemsetAsync(gtmin, 0x7f, (3 * NGT + 3240) * sizeof(float), stream);

    dim3 grid(NBLK_G, NCHUNK);
    chamfer_kernel<<<grid, 256, 0, stream>>>(gt, pbd0, pbd1, pbd2, gtmin, predmin);

    partial_kernel<<<RB, 256, 0, stream>>>(pc0, pc1, pc2, pbd0, pbd1, pbd2,
                                           ed0, ed1, ed2, li0, li1, li2,
                                           gtmin, predmin, partials);

    final_kernel<<<1, 128, 0, stream>>>(partials, out);
}

// Round 6
// 78.759 us; speedup vs baseline: 1.1052x; 1.1052x over previous
//
#include <hip/hip_runtime.h>

#define NGT 30000
#define GT_TILE 1024
#define NBLK_G 30            // ceil(30000/1024)
#define PRANGE 128           // preds per block
#define SUB 32               // preds per butterfly sub-chunk (register cap)
#define NCHUNK 27            // m0: 2, m1: 5, m2: 20 chunks of 128
#define RB 128               // reduce blocks

// ---------------------------------------------------------------------------
// Fused single-pass chamfer: grid = (NBLK_G, NCHUNK), block = 256.
// Thread: 4 gt pts in regs. Block: 128-pred range in LDS (float4+norm),
// processed as 4 sub-chunks of 32 so the per-lane min array stays in
// registers (Round-5 post-mortem: pm[64]+butterfly spilled to scratch,
// 170 MB/dispatch of HBM spill traffic).
// Each pair distance computed ONCE, feeds both sides:
//   gmin[k] (gt-side running min), pm[j] (this thread's 4-gt min for pred j).
// Per sub-chunk: 5-level register-halving butterfly (cndmask+shfl_xor+min);
// lanes 2p,2p+1 end with pred p's min over the wave's 256 gt -> atomicMin.
// atomicMin on int bits of (near-)non-negative floats: order-independent,
// deterministic; init 0x7f7f7f7f.
// ---------------------------------------------------------------------------
__global__ __launch_bounds__(256) void chamfer_kernel(
    const float* __restrict__ gt,
    const float* __restrict__ pbd0,
    const float* __restrict__ pbd1,
    const float* __restrict__ pbd2,
    float* __restrict__ gtmin,     // [3*NGT] pre-init 0x7f
    float* __restrict__ predmin)   // [3240]  pre-init 0x7f
{
    __shared__ float4 spred[PRANGE];

    const int tid = threadIdx.x;
    const int c = blockIdx.y;

    int mesh, cidx;
    if (c < 2)      { mesh = 0; cidx = c; }
    else if (c < 7) { mesh = 1; cidx = c - 2; }
    else            { mesh = 2; cidx = c - 7; }
    const int coff = cidx * PRANGE;
    const int n    = (mesh == 0) ? 156 : (mesh == 1) ? 618 : 2466;
    const int poff = (mesh == 0) ? 0   : (mesh == 1) ? 156 : 774;
    const float* pred = (mesh == 0) ? pbd0 : (mesh == 1) ? pbd1 : pbd2;
    const int np = min(PRANGE, n - coff);

    if (tid < PRANGE) {
        float4 v = make_float4(0.f, 0.f, 0.f, 3.0e38f);   // sentinel pred
        if (tid < np) {
            const int j = coff + tid;
            float px = pred[3*j], py = pred[3*j+1], pz = pred[3*j+2];
            v = make_float4(px, py, pz, px*px + py*py + pz*pz);
        }
        spred[tid] = v;
    }

    const int gbase = blockIdx.x * GT_TILE;
    float gx[4], gy[4], gz[4], g2[4], gmin[4];
    #pragma unroll
    for (int k = 0; k < 4; ++k) {
        const int g = gbase + k * 256 + tid;
        float x = 1e18f, y = 1e18f, z = 1e18f;   // sentinel gt: huge, finite
        if (g < NGT) { x = gt[3*g]; y = gt[3*g+1]; z = gt[3*g+2]; }
        gx[k] = x; gy[k] = y; gz[k] = z;
        g2[k] = x*x + y*y + z*z;
        gmin[k] = 3.0e38f;
    }
    __syncthreads();

    const int lane = tid & 63;

    // ---- 4 sub-chunks of 32 preds: fused distance + per-sub butterfly ----
    for (int s = 0; s < PRANGE / SUB; ++s) {
        float pm[SUB];
        #pragma unroll
        for (int j = 0; j < SUB; ++j) {
            const float4 p = spred[s * SUB + j];       // broadcast ds_read_b128
            float d[4];
            #pragma unroll
            for (int k = 0; k < 4; ++k) {
                float dot = gx[k]*p.x + gy[k]*p.y + gz[k]*p.z;
                float t = __fmaf_rn(dot, -2.0f, p.w);  // p2 - 2*dot
                d[k] = t + g2[k];
                gmin[k] = fminf(gmin[k], d[k]);
            }
            pm[j] = fminf(fminf(d[0], d[1]), fminf(d[2], d[3]));
        }

        // 5-level register-halving butterfly: 32 values x 64 lanes
        float r16[16];
        #pragma unroll
        for (int j = 0; j < 16; ++j) {
            float a = (lane & 32) ? pm[j + 16] : pm[j];
            r16[j] = fminf(a, __shfl_xor(a, 32, 64));
        }
        float r8[8];
        #pragma unroll
        for (int j = 0; j < 8; ++j) {
            float a = (lane & 16) ? r16[j + 8] : r16[j];
            r8[j] = fminf(a, __shfl_xor(a, 16, 64));
        }
        float r4[4];
        #pragma unroll
        for (int j = 0; j < 4; ++j) {
            float a = (lane & 8) ? r8[j + 4] : r8[j];
            r4[j] = fminf(a, __shfl_xor(a, 8, 64));
        }
        float r2[2];
        #pragma unroll
        for (int j = 0; j < 2; ++j) {
            float a = (lane & 4) ? r4[j + 2] : r4[j];
            r2[j] = fminf(a, __shfl_xor(a, 4, 64));
        }
        float a = (lane & 2) ? r2[1] : r2[0];
        float r = fminf(a, __shfl_xor(a, 2, 64));
        r = fminf(r, __shfl_xor(r, 1, 64));
        // lanes 2p, 2p+1 hold pred (s*32+p)'s min over this wave's 256 gt
        const int pj = s * SUB + (lane >> 1);
        if ((lane & 1) == 0 && pj < np)
            atomicMin((int*)(predmin + poff + coff + pj), __float_as_int(r));
    }

    // ---- gt-side atomics ----
    #pragma unroll
    for (int k = 0; k < 4; ++k) {
        const int g = gbase + k * 256 + tid;
        if (g < NGT)
            atomicMin((int*)(gtmin + mesh * NGT + g), __float_as_int(gmin[k]));
    }
}

// ---------------------------------------------------------------------------
// Partial reduce: gtmin/predmin sums + edge + laplace, RB blocks x 256.
// Deterministic: fixed index slices, fixed-order block tree reduce.
// ---------------------------------------------------------------------------
__global__ __launch_bounds__(256) void partial_kernel(
    const float* __restrict__ pc0, const float* __restrict__ pc1, const float* __restrict__ pc2,
    const float* __restrict__ pbd0, const float* __restrict__ pbd1, const float* __restrict__ pbd2,
    const int* __restrict__ ed0, const int* __restrict__ ed1, const int* __restrict__ ed2,
    const int* __restrict__ li0, const int* __restrict__ li1, const int* __restrict__ li2,
    const float* __restrict__ gtmin, const float* __restrict__ predmin,
    float* __restrict__ partials)   // [RB*4]
{
    const int   NVs[3]   = {156, 618, 2466};
    const int   NEs[3]   = {462, 1848, 7392};
    const int   poffs[3] = {0, 156, 774};
    const int   eoffs[3] = {0, 462, 2310};
    const float lapc[3]  = {0.2f, 1.0f, 1.0f};
    const float* pcs[3]  = {pc0, pc1, pc2};
    const float* pbds[3] = {pbd0, pbd1, pbd2};
    const int*   eds[3]  = {ed0, ed1, ed2};
    const int*   lis[3]  = {li0, li1, li2};

    const int tid = threadIdx.x;
    const int stride = gridDim.x * 256;
    float ch = 0.f, ed = 0.f, lp = 0.f;

    // index space: [0,90000) gtmin | [90000,93240) predmin |
    //              [93240,102942) edges | [102942,106182) laplace verts
    for (int idx = blockIdx.x * 256 + tid; idx < 106182; idx += stride) {
        if (idx < 90000) {
            ch += gtmin[idx] * (1.0f / 30000.0f);
        } else if (idx < 93240) {
            int p = idx - 90000;
            int m = (p < 156) ? 0 : (p < 774) ? 1 : 2;
            ch += predmin[p] * (1.0f / (float)NVs[m]);
        } else if (idx < 102942) {
            int e = idx - 93240;
            int m = (e < 462) ? 0 : (e < 2310) ? 1 : 2;
            int el = e - eoffs[m];
            const int* E = eds[m];
            const float* P = pcs[m];
            int a = E[2*el], b = E[2*el+1];
            float dx = P[3*a]   - P[3*b];
            float dy = P[3*a+1] - P[3*b+1];
            float dz = P[3*a+2] - P[3*b+2];
            ed += (dx*dx + dy*dy + dz*dz) * (300.0f / (float)NEs[m]);
        } else {
            int v = idx - 102942;
            int m = (v < 156) ? 0 : (v < 774) ? 1 : 2;
            int vl = v - poffs[m];
            const int* L = lis[m];
            const float* PB = pbds[m];
            const float* PC = pcs[m];
            float mvx = PB[3*vl]   - PC[3*vl];
            float mvy = PB[3*vl+1] - PC[3*vl+1];
            float mvz = PB[3*vl+2] - PC[3*vl+2];
            float sx = 0.f, sy = 0.f, sz = 0.f;
            #pragma unroll
            for (int k = 0; k < 8; ++k) {
                int nb = L[10*vl + k];
                if (nb >= 0) {
                    sx += PB[3*nb]   - PC[3*nb];
                    sy += PB[3*nb+1] - PC[3*nb+1];
                    sz += PB[3*nb+2] - PC[3*nb+2];
                }
            }
            float invdeg = 1.0f / (float)L[10*vl + 9];
            float dx = mvx - sx * invdeg;
            float dy = mvy - sy * invdeg;
            float dz = mvz - sz * invdeg;
            float t = dx*dx + dy*dy + dz*dz;
            if (m > 0) t += mvx*mvx + mvy*mvy + mvz*mvz;
            lp += t * (lapc[m] / (float)NVs[m]);
        }
    }

    __shared__ float sred[12];
    for (int off = 32; off; off >>= 1) {
        ch += __shfl_down(ch, off, 64);
        ed += __shfl_down(ed, off, 64);
        lp += __shfl_down(lp, off, 64);
    }
    const int lane = tid & 63, wid = tid >> 6;
    if (lane == 0) { sred[wid] = ch; sred[4 + wid] = ed; sred[8 + wid] = lp; }
    __syncthreads();
    if (tid == 0) {
        partials[blockIdx.x * 4 + 0] = sred[0] + sred[1] + sred[2] + sred[3];
        partials[blockIdx.x * 4 + 1] = sred[4] + sred[5] + sred[6] + sred[7];
        partials[blockIdx.x * 4 + 2] = sred[8] + sred[9] + sred[10] + sred[11];
    }
}

// ---------------------------------------------------------------------------
// Final: sum RB partials, write 4 outputs. 1 block x 128.
// ---------------------------------------------------------------------------
__global__ __launch_bounds__(128) void final_kernel(
    const float* __restrict__ partials, float* __restrict__ out)
{
    const int tid = threadIdx.x;
    float ch = partials[4*tid], ed = partials[4*tid+1], lp = partials[4*tid+2];
    __shared__ float s[6];
    for (int off = 32; off; off >>= 1) {
        ch += __shfl_down(ch, off, 64);
        ed += __shfl_down(ed, off, 64);
        lp += __shfl_down(lp, off, 64);
    }
    if ((tid & 63) == 0) {
        int w = tid >> 6;
        s[w] = ch; s[2 + w] = ed; s[4 + w] = lp;
    }
    __syncthreads();
    if (tid == 0) {
        float c = s[0] + s[1], e = s[2] + s[3], l = s[4] + s[5];
        out[0] = 100.0f * c + 0.1f * e + 0.3f * l;
        out[1] = c;
        out[2] = e;
        out[3] = l;
    }
}

extern "C" void kernel_launch(void* const* d_in, const int* in_sizes, int n_in,
                              void* d_out, int out_size, void* d_ws, size_t ws_size,
                              hipStream_t stream) {
    const float* gt   = (const float*)d_in[0];
    const float* pc0  = (const float*)d_in[1];
    const float* pbd0 = (const float*)d_in[2];
    const int*   ed0  = (const int*)  d_in[3];
    const int*   li0  = (const int*)  d_in[4];
    const float* pc1  = (const float*)d_in[5];
    const float* pbd1 = (const float*)d_in[6];
    const int*   ed1  = (const int*)  d_in[7];
    const int*   li1  = (const int*)  d_in[8];
    const float* pc2  = (const float*)d_in[9];
    const float* pbd2 = (const float*)d_in[10];
    const int*   ed2  = (const int*)  d_in[11];
    const int*   li2  = (const int*)  d_in[12];

    float* ws       = (float*)d_ws;
    float* gtmin    = ws;                    // 3*NGT floats
    float* predmin  = ws + 3 * NGT;          // 3240 floats
    float* partials = ws + 3 * NGT + 3240;   // RB*4 floats
    float* out      = (float*)d_out;

    hipMemsetAsync(gtmin, 0x7f, (3 * NGT + 3240) * sizeof(float), stream);

    dim3 grid(NBLK_G, NCHUNK);
    chamfer_kernel<<<grid, 256, 0, stream>>>(gt, pbd0, pbd1, pbd2, gtmin, predmin);

    partial_kernel<<<RB, 256, 0, stream>>>(pc0, pc1, pc2, pbd0, pbd1, pbd2,
                                           ed0, ed1, ed2, li0, li1, li2,
                                           gtmin, predmin, partials);

    final_kernel<<<1, 128, 0, stream>>>(partials, out);
}

// Round 7
// 66.012 us; speedup vs baseline: 1.3187x; 1.1931x over previous
//
#include <hip/hip_runtime.h>

#define NGT 30000
#define GT_TILE 1024
#define NBLK_G 30            // ceil(30000/1024)
#define PRANGE 128           // preds per block
#define SUB 32               // preds per butterfly sub-chunk (register cap)
#define NCHUNK 27            // m0: 2, m1: 5, m2: 20 chunks of 128
#define RB 128               // reduce blocks

// ---------------------------------------------------------------------------
// Fused single-pass chamfer: grid = (NBLK_G, NCHUNK), block = 256.
// Thread: 4 gt pts in regs. Block: 128-pred range in LDS (float4+norm),
// processed as 4 sub-chunks of 32 (per-lane pm[] stays in registers).
// R6 post-mortem: full unroll hoisted ALL 32 ds_read_b128 to the loop head
// (32 x float4 = 128 VGPRs in flight) -> allocator capped at 92 and spilled
// ~80 MB/dispatch to scratch. Fix: sched_barrier(0) every 4 iterations caps
// loads-in-flight at 4; __launch_bounds__(256,2) raises the VGPR budget.
// Each pair distance computed ONCE, feeds both sides:
//   gmin[k] (gt-side running min), pm[j] (this thread's 4-gt min for pred j).
// Per sub-chunk: 5-level register-halving butterfly (cndmask+shfl_xor+min);
// even lanes end with pred (s*32 + lane/2)'s min over the wave's 256 gt
// -> global atomicMin. atomicMin on int bits of non-negative floats:
// order-independent, deterministic; init 0x7f7f7f7f.
// ---------------------------------------------------------------------------
__global__ __launch_bounds__(256, 2) void chamfer_kernel(
    const float* __restrict__ gt,
    const float* __restrict__ pbd0,
    const float* __restrict__ pbd1,
    const float* __restrict__ pbd2,
    float* __restrict__ gtmin,     // [3*NGT] pre-init 0x7f
    float* __restrict__ predmin)   // [3240]  pre-init 0x7f
{
    __shared__ float4 spred[PRANGE];

    const int tid = threadIdx.x;
    const int c = blockIdx.y;

    int mesh, cidx;
    if (c < 2)      { mesh = 0; cidx = c; }
    else if (c < 7) { mesh = 1; cidx = c - 2; }
    else            { mesh = 2; cidx = c - 7; }
    const int coff = cidx * PRANGE;
    const int n    = (mesh == 0) ? 156 : (mesh == 1) ? 618 : 2466;
    const int poff = (mesh == 0) ? 0   : (mesh == 1) ? 156 : 774;
    const float* pred = (mesh == 0) ? pbd0 : (mesh == 1) ? pbd1 : pbd2;
    const int np = min(PRANGE, n - coff);

    if (tid < PRANGE) {
        float4 v = make_float4(0.f, 0.f, 0.f, 3.0e38f);   // sentinel pred
        if (tid < np) {
            const int j = coff + tid;
            float px = pred[3*j], py = pred[3*j+1], pz = pred[3*j+2];
            v = make_float4(px, py, pz, px*px + py*py + pz*pz);
        }
        spred[tid] = v;
    }

    const int gbase = blockIdx.x * GT_TILE;
    float gx[4], gy[4], gz[4], g2[4], gmin[4];
    #pragma unroll
    for (int k = 0; k < 4; ++k) {
        const int g = gbase + k * 256 + tid;
        float x = 1e18f, y = 1e18f, z = 1e18f;   // sentinel gt: huge, finite
        if (g < NGT) { x = gt[3*g]; y = gt[3*g+1]; z = gt[3*g+2]; }
        gx[k] = x; gy[k] = y; gz[k] = z;
        g2[k] = x*x + y*y + z*z;
        gmin[k] = 3.0e38f;
    }
    __syncthreads();

    const int lane = tid & 63;

    // ---- 4 sub-chunks of 32 preds: fused distance + per-sub butterfly ----
    for (int s = 0; s < PRANGE / SUB; ++s) {
        float pm[SUB];
        #pragma unroll
        for (int j = 0; j < SUB; ++j) {
            const float4 p = spred[s * SUB + j];       // broadcast ds_read_b128
            float d[4];
            #pragma unroll
            for (int k = 0; k < 4; ++k) {
                float dot = gx[k]*p.x + gy[k]*p.y + gz[k]*p.z;
                float t = __fmaf_rn(dot, -2.0f, p.w);  // p2 - 2*dot
                d[k] = t + g2[k];
                gmin[k] = fminf(gmin[k], d[k]);
            }
            pm[j] = fminf(fminf(d[0], d[1]), fminf(d[2], d[3]));
            // stop the scheduler from hoisting all 32 ds_reads (R6 spill)
            if ((j & 3) == 3) __builtin_amdgcn_sched_barrier(0);
        }

        // 5-level register-halving butterfly: 32 values x 64 lanes
        float r16[16];
        #pragma unroll
        for (int j = 0; j < 16; ++j) {
            float a = (lane & 32) ? pm[j + 16] : pm[j];
            r16[j] = fminf(a, __shfl_xor(a, 32, 64));
        }
        float r8[8];
        #pragma unroll
        for (int j = 0; j < 8; ++j) {
            float a = (lane & 16) ? r16[j + 8] : r16[j];
            r8[j] = fminf(a, __shfl_xor(a, 16, 64));
        }
        float r4[4];
        #pragma unroll
        for (int j = 0; j < 4; ++j) {
            float a = (lane & 8) ? r8[j + 4] : r8[j];
            r4[j] = fminf(a, __shfl_xor(a, 8, 64));
        }
        float r2[2];
        #pragma unroll
        for (int j = 0; j < 2; ++j) {
            float a = (lane & 4) ? r4[j + 2] : r4[j];
            r2[j] = fminf(a, __shfl_xor(a, 4, 64));
        }
        float a = (lane & 2) ? r2[1] : r2[0];
        float r = fminf(a, __shfl_xor(a, 2, 64));
        r = fminf(r, __shfl_xor(r, 1, 64));
        // lanes 2p, 2p+1 hold pred (s*32+p)'s min over this wave's 256 gt
        const int pj = s * SUB + (lane >> 1);
        if ((lane & 1) == 0 && pj < np)
            atomicMin((int*)(predmin + poff + coff + pj), __float_as_int(r));
    }

    // ---- gt-side atomics ----
    #pragma unroll
    for (int k = 0; k < 4; ++k) {
        const int g = gbase + k * 256 + tid;
        if (g < NGT)
            atomicMin((int*)(gtmin + mesh * NGT + g), __float_as_int(gmin[k]));
    }
}

// ---------------------------------------------------------------------------
// Partial reduce: gtmin/predmin sums + edge + laplace, RB blocks x 256.
// Deterministic: fixed index slices, fixed-order block tree reduce.
// ---------------------------------------------------------------------------
__global__ __launch_bounds__(256) void partial_kernel(
    const float* __restrict__ pc0, const float* __restrict__ pc1, const float* __restrict__ pc2,
    const float* __restrict__ pbd0, const float* __restrict__ pbd1, const float* __restrict__ pbd2,
    const int* __restrict__ ed0, const int* __restrict__ ed1, const int* __restrict__ ed2,
    const int* __restrict__ li0, const int* __restrict__ li1, const int* __restrict__ li2,
    const float* __restrict__ gtmin, const float* __restrict__ predmin,
    float* __restrict__ partials)   // [RB*4]
{
    const int   NVs[3]   = {156, 618, 2466};
    const int   NEs[3]   = {462, 1848, 7392};
    const int   poffs[3] = {0, 156, 774};
    const int   eoffs[3] = {0, 462, 2310};
    const float lapc[3]  = {0.2f, 1.0f, 1.0f};
    const float* pcs[3]  = {pc0, pc1, pc2};
    const float* pbds[3] = {pbd0, pbd1, pbd2};
    const int*   eds[3]  = {ed0, ed1, ed2};
    const int*   lis[3]  = {li0, li1, li2};

    const int tid = threadIdx.x;
    const int stride = gridDim.x * 256;
    float ch = 0.f, ed = 0.f, lp = 0.f;

    // index space: [0,90000) gtmin | [90000,93240) predmin |
    //              [93240,102942) edges | [102942,106182) laplace verts
    for (int idx = blockIdx.x * 256 + tid; idx < 106182; idx += stride) {
        if (idx < 90000) {
            ch += gtmin[idx] * (1.0f / 30000.0f);
        } else if (idx < 93240) {
            int p = idx - 90000;
            int m = (p < 156) ? 0 : (p < 774) ? 1 : 2;
            ch += predmin[p] * (1.0f / (float)NVs[m]);
        } else if (idx < 102942) {
            int e = idx - 93240;
            int m = (e < 462) ? 0 : (e < 2310) ? 1 : 2;
            int el = e - eoffs[m];
            const int* E = eds[m];
            const float* P = pcs[m];
            int a = E[2*el], b = E[2*el+1];
            float dx = P[3*a]   - P[3*b];
            float dy = P[3*a+1] - P[3*b+1];
            float dz = P[3*a+2] - P[3*b+2];
            ed += (dx*dx + dy*dy + dz*dz) * (300.0f / (float)NEs[m]);
        } else {
            int v = idx - 102942;
            int m = (v < 156) ? 0 : (v < 774) ? 1 : 2;
            int vl = v - poffs[m];
            const int* L = lis[m];
            const float* PB = pbds[m];
            const float* PC = pcs[m];
            float mvx = PB[3*vl]   - PC[3*vl];
            float mvy = PB[3*vl+1] - PC[3*vl+1];
            float mvz = PB[3*vl+2] - PC[3*vl+2];
            float sx = 0.f, sy = 0.f, sz = 0.f;
            #pragma unroll
            for (int k = 0; k < 8; ++k) {
                int nb = L[10*vl + k];
                if (nb >= 0) {
                    sx += PB[3*nb]   - PC[3*nb];
                    sy += PB[3*nb+1] - PC[3*nb+1];
                    sz += PB[3*nb+2] - PC[3*nb+2];
                }
            }
            float invdeg = 1.0f / (float)L[10*vl + 9];
            float dx = mvx - sx * invdeg;
            float dy = mvy - sy * invdeg;
            float dz = mvz - sz * invdeg;
            float t = dx*dx + dy*dy + dz*dz;
            if (m > 0) t += mvx*mvx + mvy*mvy + mvz*mvz;
            lp += t * (lapc[m] / (float)NVs[m]);
        }
    }

    __shared__ float sred[12];
    for (int off = 32; off; off >>= 1) {
        ch += __shfl_down(ch, off, 64);
        ed += __shfl_down(ed, off, 64);
        lp += __shfl_down(lp, off, 64);
    }
    const int lane = tid & 63, wid = tid >> 6;
    if (lane == 0) { sred[wid] = ch; sred[4 + wid] = ed; sred[8 + wid] = lp; }
    __syncthreads();
    if (tid == 0) {
        partials[blockIdx.x * 4 + 0] = sred[0] + sred[1] + sred[2] + sred[3];
        partials[blockIdx.x * 4 + 1] = sred[4] + sred[5] + sred[6] + sred[7];
        partials[blockIdx.x * 4 + 2] = sred[8] + sred[9] + sred[10] + sred[11];
    }
}

// ---------------------------------------------------------------------------
// Final: sum RB partials, write 4 outputs. 1 block x 128.
// ---------------------------------------------------------------------------
__global__ __launch_bounds__(128) void final_kernel(
    const float* __restrict__ partials, float* __restrict__ out)
{
    const int tid = threadIdx.x;
    float ch = partials[4*tid], ed = partials[4*tid+1], lp = partials[4*tid+2];
    __shared__ float s[6];
    for (int off = 32; off; off >>= 1) {
        ch += __shfl_down(ch, off, 64);
        ed += __shfl_down(ed, off, 64);
        lp += __shfl_down(lp, off, 64);
    }
    if ((tid & 63) == 0) {
        int w = tid >> 6;
        s[w] = ch; s[2 + w] = ed; s[4 + w] = lp;
    }
    __syncthreads();
    if (tid == 0) {
        float c = s[0] + s[1], e = s[2] + s[3], l = s[4] + s[5];
        out[0] = 100.0f * c + 0.1f * e + 0.3f * l;
        out[1] = c;
        out[2] = e;
        out[3] = l;
    }
}

extern "C" void kernel_launch(void* const* d_in, const int* in_sizes, int n_in,
                              void* d_out, int out_size, void* d_ws, size_t ws_size,
                              hipStream_t stream) {
    const float* gt   = (const float*)d_in[0];
    const float* pc0  = (const float*)d_in[1];
    const float* pbd0 = (const float*)d_in[2];
    const int*   ed0  = (const int*)  d_in[3];
    const int*   li0  = (const int*)  d_in[4];
    const float* pc1  = (const float*)d_in[5];
    const float* pbd1 = (const float*)d_in[6];
    const int*   ed1  = (const int*)  d_in[7];
    const int*   li1  = (const int*)  d_in[8];
    const float* pc2  = (const float*)d_in[9];
    const float* pbd2 = (const float*)d_in[10];
    const int*   ed2  = (const int*)  d_in[11];
    const int*   li2  = (const int*)  d_in[12];

    float* ws       = (float*)d_ws;
    float* gtmin    = ws;                    // 3*NGT floats
    float* predmin  = ws + 3 * NGT;          // 3240 floats
    float* partials = ws + 3 * NGT + 3240;   // RB*4 floats
    float* out      = (float*)d_out;

    hipMemsetAsync(gtmin, 0x7f, (3 * NGT + 3240) * sizeof(float), stream);

    dim3 grid(NBLK_G, NCHUNK);
    chamfer_kernel<<<grid, 256, 0, stream>>>(gt, pbd0, pbd1, pbd2, gtmin, predmin);

    partial_kernel<<<RB, 256, 0, stream>>>(pc0, pc1, pc2, pbd0, pbd1, pbd2,
                                           ed0, ed1, ed2, li0, li1, li2,
                                           gtmin, predmin, partials);

    final_kernel<<<1, 128, 0, stream>>>(partials, out);
}

// Round 8
// 50.500 us; speedup vs baseline: 1.7237x; 1.3072x over previous
//
#include <hip/hip_runtime.h>

#define NGT 30000
#define GT_TILE 512
#define NBLK_G 59            // ceil(30000/512)
#define PRANGE 128           // preds per block
#define NCHUNK 27            // m0: 2, m1: 5, m2: 20 chunks of 128
#define RB 128               // reduce blocks

// ---------------------------------------------------------------------------
// Two-phase chamfer (spill-free R4 structure, occupancy-tuned).
// grid = (NBLK_G, NCHUNK), block = 256. LDS: sgt[512] + spred[128] float4
// (10 KB). Thread: 2 gt pts in regs. R5-R7 post-mortem: any per-lane
// pred-min array (pm[32+]) spills to scratch (80-170 MB/dispatch HBM
// write traffic) no matter the scheduling hints -> two-phase recompute
// (10 ops/pair vs 6.75 fused) is strictly faster in practice.
// Phase 1: per pred j (broadcast ds_read_b128), 2 distances, gt-side
//          running min -> atomicMin gtmin.
// Phase 2: 8-lane groups own 4 preds in regs; lane s scans interleaved
//          slice sgt[k*8+s] (8 distinct float4 addrs/wave -> 32 banks,
//          conflict-free); 3-level shfl_xor combine -> atomicMin predmin.
// d = side2 + (other2 - 2*dot) with the owner-side norm added after the
// min. Sentinel preds carry w=3e38 (never win); sentinel gt carry 1e18
// coords (never win pred-side). atomicMin on int bits of non-negative
// floats: exact, order-independent, deterministic; init 0x7f7f7f7f.
// ---------------------------------------------------------------------------
__global__ __launch_bounds__(256) void chamfer_kernel(
    const float* __restrict__ gt,
    const float* __restrict__ pbd0,
    const float* __restrict__ pbd1,
    const float* __restrict__ pbd2,
    float* __restrict__ gtmin,     // [3*NGT] pre-init 0x7f
    float* __restrict__ predmin)   // [3240]  pre-init 0x7f
{
    __shared__ float4 sgt[GT_TILE];
    __shared__ float4 spred[PRANGE];

    const int tid = threadIdx.x;
    const int c = blockIdx.y;

    int mesh, cidx;
    if (c < 2)      { mesh = 0; cidx = c; }
    else if (c < 7) { mesh = 1; cidx = c - 2; }
    else            { mesh = 2; cidx = c - 7; }
    const int coff = cidx * PRANGE;
    const int n    = (mesh == 0) ? 156 : (mesh == 1) ? 618 : 2466;
    const int poff = (mesh == 0) ? 0   : (mesh == 1) ? 156 : 774;
    const float* pred = (mesh == 0) ? pbd0 : (mesh == 1) ? pbd1 : pbd2;
    const int np = min(PRANGE, n - coff);

    if (tid < PRANGE) {
        float4 v = make_float4(0.f, 0.f, 0.f, 3.0e38f);   // sentinel pred
        if (tid < np) {
            const int j = coff + tid;
            float px = pred[3*j], py = pred[3*j+1], pz = pred[3*j+2];
            v = make_float4(px, py, pz, px*px + py*py + pz*pz);
        }
        spred[tid] = v;
    }

    const int gbase = blockIdx.x * GT_TILE;
    float gx[2], gy[2], gz[2], g2[2], gmin[2];
    #pragma unroll
    for (int k = 0; k < 2; ++k) {
        const int g = gbase + k * 256 + tid;
        float x = 1e18f, y = 1e18f, z = 1e18f;   // sentinel gt: huge, finite
        if (g < NGT) { x = gt[3*g]; y = gt[3*g+1]; z = gt[3*g+2]; }
        gx[k] = x; gy[k] = y; gz[k] = z;
        g2[k] = x*x + y*y + z*z;
        gmin[k] = 3.0e38f;
        sgt[k * 256 + tid] = make_float4(x, y, z, g2[k]);
    }
    __syncthreads();

    // ---- phase 1: gt-side min over the 128-pred chunk (broadcast reads) ----
    #pragma unroll 8
    for (int j = 0; j < PRANGE; ++j) {
        const float4 p = spred[j];                 // broadcast ds_read_b128
        #pragma unroll
        for (int k = 0; k < 2; ++k) {
            float dot = gx[k]*p.x + gy[k]*p.y + gz[k]*p.z;
            float t = __fmaf_rn(dot, -2.0f, p.w);  // p2 - 2*dot
            gmin[k] = fminf(gmin[k], t);
        }
    }
    #pragma unroll
    for (int k = 0; k < 2; ++k) {
        const int g = gbase + k * 256 + tid;
        if (g < NGT)
            atomicMin((int*)(gtmin + mesh * NGT + g),
                      __float_as_int(gmin[k] + g2[k]));
    }

    // ---- phase 2: pred-side min; 8-lane groups x 4 preds in regs ----
    {
        const int grp = tid >> 3;                  // 0..31 -> preds 4g..4g+3
        const int s   = tid & 7;                   // interleaved slice
        float4 p[4];
        #pragma unroll
        for (int r = 0; r < 4; ++r) p[r] = spred[4*grp + r];
        float mn[4] = {3.0e38f, 3.0e38f, 3.0e38f, 3.0e38f};
        #pragma unroll 4
        for (int k = 0; k < GT_TILE / 8; ++k) {
            const float4 q = sgt[k * 8 + s];       // 8 addrs -> banks 0..31
            #pragma unroll
            for (int r = 0; r < 4; ++r) {
                float dot = q.x*p[r].x + q.y*p[r].y + q.z*p[r].z;
                float t = __fmaf_rn(dot, -2.0f, q.w);  // g2 - 2*dot
                mn[r] = fminf(mn[r], t);
            }
        }
        #pragma unroll
        for (int off = 1; off < 8; off <<= 1) {
            #pragma unroll
            for (int r = 0; r < 4; ++r)
                mn[r] = fminf(mn[r], __shfl_xor(mn[r], off, 64));
        }
        if (s == 0) {
            #pragma unroll
            for (int r = 0; r < 4; ++r) {
                const int pj = 4*grp + r;
                if (pj < np)
                    atomicMin((int*)(predmin + poff + coff + pj),
                              __float_as_int(mn[r] + p[r].w));
            }
        }
    }
}

// ---------------------------------------------------------------------------
// Partial reduce: gtmin/predmin sums + edge + laplace, RB blocks x 256.
// Deterministic: fixed index slices, fixed-order block tree reduce.
// ---------------------------------------------------------------------------
__global__ __launch_bounds__(256) void partial_kernel(
    const float* __restrict__ pc0, const float* __restrict__ pc1, const float* __restrict__ pc2,
    const float* __restrict__ pbd0, const float* __restrict__ pbd1, const float* __restrict__ pbd2,
    const int* __restrict__ ed0, const int* __restrict__ ed1, const int* __restrict__ ed2,
    const int* __restrict__ li0, const int* __restrict__ li1, const int* __restrict__ li2,
    const float* __restrict__ gtmin, const float* __restrict__ predmin,
    float* __restrict__ partials)   // [RB*4]
{
    const int   NVs[3]   = {156, 618, 2466};
    const int   NEs[3]   = {462, 1848, 7392};
    const int   poffs[3] = {0, 156, 774};
    const int   eoffs[3] = {0, 462, 2310};
    const float lapc[3]  = {0.2f, 1.0f, 1.0f};
    const float* pcs[3]  = {pc0, pc1, pc2};
    const float* pbds[3] = {pbd0, pbd1, pbd2};
    const int*   eds[3]  = {ed0, ed1, ed2};
    const int*   lis[3]  = {li0, li1, li2};

    const int tid = threadIdx.x;
    const int stride = gridDim.x * 256;
    float ch = 0.f, ed = 0.f, lp = 0.f;

    // index space: [0,90000) gtmin | [90000,93240) predmin |
    //              [93240,102942) edges | [102942,106182) laplace verts
    for (int idx = blockIdx.x * 256 + tid; idx < 106182; idx += stride) {
        if (idx < 90000) {
            ch += gtmin[idx] * (1.0f / 30000.0f);
        } else if (idx < 93240) {
            int p = idx - 90000;
            int m = (p < 156) ? 0 : (p < 774) ? 1 : 2;
            ch += predmin[p] * (1.0f / (float)NVs[m]);
        } else if (idx < 102942) {
            int e = idx - 93240;
            int m = (e < 462) ? 0 : (e < 2310) ? 1 : 2;
            int el = e - eoffs[m];
            const int* E = eds[m];
            const float* P = pcs[m];
            int a = E[2*el], b = E[2*el+1];
            float dx = P[3*a]   - P[3*b];
            float dy = P[3*a+1] - P[3*b+1];
            float dz = P[3*a+2] - P[3*b+2];
            ed += (dx*dx + dy*dy + dz*dz) * (300.0f / (float)NEs[m]);
        } else {
            int v = idx - 102942;
            int m = (v < 156) ? 0 : (v < 774) ? 1 : 2;
            int vl = v - poffs[m];
            const int* L = lis[m];
            const float* PB = pbds[m];
            const float* PC = pcs[m];
            float mvx = PB[3*vl]   - PC[3*vl];
            float mvy = PB[3*vl+1] - PC[3*vl+1];
            float mvz = PB[3*vl+2] - PC[3*vl+2];
            float sx = 0.f, sy = 0.f, sz = 0.f;
            #pragma unroll
            for (int k = 0; k < 8; ++k) {
                int nb = L[10*vl + k];
                if (nb >= 0) {
                    sx += PB[3*nb]   - PC[3*nb];
                    sy += PB[3*nb+1] - PC[3*nb+1];
                    sz += PB[3*nb+2] - PC[3*nb+2];
                }
            }
            float invdeg = 1.0f / (float)L[10*vl + 9];
            float dx = mvx - sx * invdeg;
            float dy = mvy - sy * invdeg;
            float dz = mvz - sz * invdeg;
            float t = dx*dx + dy*dy + dz*dz;
            if (m > 0) t += mvx*mvx + mvy*mvy + mvz*mvz;
            lp += t * (lapc[m] / (float)NVs[m]);
        }
    }

    __shared__ float sred[12];
    for (int off = 32; off; off >>= 1) {
        ch += __shfl_down(ch, off, 64);
        ed += __shfl_down(ed, off, 64);
        lp += __shfl_down(lp, off, 64);
    }
    const int lane = tid & 63, wid = tid >> 6;
    if (lane == 0) { sred[wid] = ch; sred[4 + wid] = ed; sred[8 + wid] = lp; }
    __syncthreads();
    if (tid == 0) {
        partials[blockIdx.x * 4 + 0] = sred[0] + sred[1] + sred[2] + sred[3];
        partials[blockIdx.x * 4 + 1] = sred[4] + sred[5] + sred[6] + sred[7];
        partials[blockIdx.x * 4 + 2] = sred[8] + sred[9] + sred[10] + sred[11];
    }
}

// ---------------------------------------------------------------------------
// Final: sum RB partials, write 4 outputs. 1 block x 128.
// ---------------------------------------------------------------------------
__global__ __launch_bounds__(128) void final_kernel(
    const float* __restrict__ partials, float* __restrict__ out)
{
    const int tid = threadIdx.x;
    float ch = partials[4*tid], ed = partials[4*tid+1], lp = partials[4*tid+2];
    __shared__ float s[6];
    for (int off = 32; off; off >>= 1) {
        ch += __shfl_down(ch, off, 64);
        ed += __shfl_down(ed, off, 64);
        lp += __shfl_down(lp, off, 64);
    }
    if ((tid & 63) == 0) {
        int w = tid >> 6;
        s[w] = ch; s[2 + w] = ed; s[4 + w] = lp;
    }
    __syncthreads();
    if (tid == 0) {
        float c = s[0] + s[1], e = s[2] + s[3], l = s[4] + s[5];
        out[0] = 100.0f * c + 0.1f * e + 0.3f * l;
        out[1] = c;
        out[2] = e;
        out[3] = l;
    }
}

extern "C" void kernel_launch(void* const* d_in, const int* in_sizes, int n_in,
                              void* d_out, int out_size, void* d_ws, size_t ws_size,
                              hipStream_t stream) {
    const float* gt   = (const float*)d_in[0];
    const float* pc0  = (const float*)d_in[1];
    const float* pbd0 = (const float*)d_in[2];
    const int*   ed0  = (const int*)  d_in[3];
    const int*   li0  = (const int*)  d_in[4];
    const float* pc1  = (const float*)d_in[5];
    const float* pbd1 = (const float*)d_in[6];
    const int*   ed1  = (const int*)  d_in[7];
    const int*   li1  = (const int*)  d_in[8];
    const float* pc2  = (const float*)d_in[9];
    const float* pbd2 = (const float*)d_in[10];
    const int*   ed2  = (const int*)  d_in[11];
    const int*   li2  = (const int*)  d_in[12];

    float* ws       = (float*)d_ws;
    float* gtmin    = ws;                    // 3*NGT floats
    float* predmin  = ws + 3 * NGT;          // 3240 floats
    float* partials = ws + 3 * NGT + 3240;   // RB*4 floats
    float* out      = (float*)d_out;

    hipMemsetAsync(gtmin, 0x7f, (3 * NGT + 3240) * sizeof(float), stream);

    dim3 grid(NBLK_G, NCHUNK);
    chamfer_kernel<<<grid, 256, 0, stream>>>(gt, pbd0, pbd1, pbd2, gtmin, predmin);

    partial_kernel<<<RB, 256, 0, stream>>>(pc0, pc1, pc2, pbd0, pbd1, pbd2,
                                           ed0, ed1, ed2, li0, li1, li2,
                                           gtmin, predmin, partials);

    final_kernel<<<1, 128, 0, stream>>>(partials, out);
}